// Round 5
// baseline (476.043 us; speedup 1.0000x reference)
//
#include <hip/hip_runtime.h>
#include <hip/hip_bf16.h>

typedef unsigned int u32;
typedef unsigned short u16;
typedef short short8 __attribute__((ext_vector_type(8)));
typedef float f32x4 __attribute__((ext_vector_type(4)));

#define R_ 32
#define KEYS_PER_B 2048     // 4 wavegroups * 32 relations * 16 rows
#define SORT_STRIDE 1024    // fixed per-chunk slots in sorted[] (mean 767, +9 sigma)
#define CAP 16              // per-wave per-relation buffered edge gathers

static __device__ __forceinline__ u16 f2bf(float f) {
  u32 u = __float_as_uint(f);
  u = (u + 0x7FFFu + ((u >> 16) & 1u)) >> 16;   // RNE
  return (u16)u;
}
static __device__ __forceinline__ u32 pk2(float a, float b) {
  __hip_bfloat162 h2 = __float22bfloat162_rn(make_float2(a, b));
  union { __hip_bfloat162 h; u32 u; } cv; cv.h = h2; return cv.u;
}

static __device__ __forceinline__ int sort_key(int tgt, int r) {
  return (tgt >> 6) * KEYS_PER_B + ((tgt >> 4) & 3) * 512 + r * 16 + (tgt & 15);
}

// ---- fused: x fp32->bf16 convert + W/W_root pack + hist ----
__global__ void k_pre(const float* __restrict__ x, const float* __restrict__ W,
                      const float* __restrict__ Wroot, const int* __restrict__ ei,
                      const int* __restrict__ et, u16* __restrict__ xb,
                      u16* __restrict__ wp, u16* __restrict__ wrootp,
                      int* __restrict__ hist, int n4, int E, int convNB, int packNB) {
  const int bb = (int)blockIdx.x;
  if (bb < convNB) {
    int i = bb * 256 + threadIdx.x;
    if (i >= n4) return;
    const float4 f = ((const float4*)x)[i];
    u32 lo = (u32)f2bf(f.x) | ((u32)f2bf(f.y) << 16);
    u32 hi = (u32)f2bf(f.z) | ((u32)f2bf(f.w) << 16);
    ((uint2*)xb)[i] = make_uint2(lo, hi);
  } else if (bb < convNB + packNB) {
    int tid = (bb - convNB) * 256 + threadIdx.x;
    if (tid >= 33 * 2048) return;
    int lane = tid & 63;
    int ks = (tid >> 6) & 3;
    int ct = (tid >> 8) & 7;
    int rr = tid >> 11;
    int i0 = ks * 32 + (lane >> 4) * 8;
    int o  = ct * 16 + (lane & 15);
    const float* src = (rr < 32) ? (W + (size_t)rr * (128 * 128)) : Wroot;
    u16* dst = (rr < 32) ? (wp + ((size_t)((rr * 8 + ct) * 4 + ks) * 64 + lane) * 8)
                         : (wrootp + ((size_t)((ct * 4 + ks) * 64 + lane)) * 8);
#pragma unroll
    for (int j = 0; j < 8; ++j) dst[j] = f2bf(src[(size_t)(i0 + j) * 128 + o]);
  } else {
    int e4 = ((bb - convNB - packNB) * 256 + threadIdx.x) * 4;
    if (e4 >= E) return;
    const int4 tg = *(const int4*)(ei + E + e4);
    const int4 rt = *(const int4*)(et + e4);
    atomicAdd(hist + sort_key(tg.x, rt.x), 1);
    atomicAdd(hist + sort_key(tg.y, rt.y), 1);
    atomicAdd(hist + sort_key(tg.z, rt.z), 1);
    atomicAdd(hist + sort_key(tg.w, rt.w), 1);
  }
}

// ---- per-chunk exclusive scan (chunk = 2048 keys = one batch) ----
__global__ __launch_bounds__(256) void k_scan_local(const int* __restrict__ hist,
                                                    int* __restrict__ offs) {
  __shared__ int wsum[4];
  int b = blockIdx.x, t = threadIdx.x;
  size_t base = (size_t)b * KEYS_PER_B + (size_t)t * 8;
  int4 a = *(const int4*)(hist + base);
  int4 c = *(const int4*)(hist + base + 4);
  int v[8] = {a.x, a.y, a.z, a.w, c.x, c.y, c.z, c.w};
  int s = 0;
#pragma unroll
  for (int i = 0; i < 8; ++i) s += v[i];
  int lane = t & 63, w = t >> 6;
  int x = s;
#pragma unroll
  for (int off = 1; off < 64; off <<= 1) {
    int y = __shfl_up(x, off);
    if (lane >= off) x += y;
  }
  if (lane == 63) wsum[w] = x;
  __syncthreads();
  int wb = 0;
  for (int i = 0; i < w; ++i) wb += wsum[i];
  int ex = wb + x - s;
  int o[8];
#pragma unroll
  for (int i = 0; i < 8; ++i) { o[i] = ex; ex += v[i]; }
  *(int4*)(offs + base) = make_int4(o[0], o[1], o[2], o[3]);
  *(int4*)(offs + base + 4) = make_int4(o[4], o[5], o[6], o[7]);
}

// ---- scatter (4 edges/thread); offs[key] becomes per-key chunk-local END ----
__global__ void k_scatter(const int* __restrict__ ei, const int* __restrict__ et,
                          int* __restrict__ offs, u32* __restrict__ sorted, int E) {
  int e4 = (blockIdx.x * 256 + threadIdx.x) * 4;
  if (e4 >= E) return;
  const int4 sr = *(const int4*)(ei + e4);
  const int4 tg = *(const int4*)(ei + E + e4);
  const int4 rt = *(const int4*)(et + e4);
#pragma unroll
  for (int j = 0; j < 4; ++j) {
    int src = (&sr.x)[j], tgt = (&tg.x)[j], r = (&rt.x)[j];
    int p = atomicAdd(offs + sort_key(tgt, r), 1);
    if (p < SORT_STRIDE)
      sorted[(size_t)(tgt >> 6) * SORT_STRIDE + p] = (u32)src | ((u32)(tgt & 63) << 16);
  }
}

// ---- main batch kernel: ZERO barriers, fully independent waves ----
// Wave w owns rows w*16..w*16+15 (M=16 GEMM). Private LDS slice; per relation:
// consume prefetched gathers (run-detect, avg ~6 edges), flush non-empty rows,
// mask-select A fragments (stale rows -> 0), 32 MFMAs with double-staged B.
__global__ __launch_bounds__(256) void k_batch(
    const u16* __restrict__ xb, const u16* __restrict__ wp, const u16* __restrict__ wrootp,
    const float* __restrict__ bias, const u32* __restrict__ sorted,
    const int* __restrict__ offs, float* __restrict__ h, int N) {
  __shared__ u16 aggb[64 * 136];   // 17.4 KB; wave w uses rows w*16..w*16+15 only
  const int b = blockIdx.x, t = threadIdx.x;
  const int lane = t & 63, w = t >> 6;
  const int m = lane & 15, q = lane >> 4;
  const int nb = b * 64;
  const int wkBase = b * KEYS_PER_B + w * 512;
  const u32* srt = sorted + (size_t)b * SORT_STRIDE;
  u16* myAgg = aggb + (size_t)(w * 16) * 136;
  const short8 zero8 = {0, 0, 0, 0, 0, 0, 0, 0};

  // per-lane register table of this wave's 32 segment ends
  const int evE = offs[wkBase + (lane & 31) * 16 + 15];
  int sCur = (w == 0) ? 0 : offs[wkBase - 1];
  int eCur = __builtin_amdgcn_readlane(evE, 0);

  // prologue: descriptors + gathers for relation 0
  u32 evC = srt[sCur + m];
  int nB = min(eCur - sCur, CAP);
  u32 xv[CAP];
#pragma unroll
  for (int j = 0; j < CAP; ++j) {
    if (j < nB) {
      int e = __builtin_amdgcn_readlane((int)evC, j);
      xv[j] = *(const u32*)(xb + (size_t)(e & 0xFFFF) * 128 + 2 * lane);
    }
  }

  f32x4 acc[8];
#pragma unroll
  for (int ct = 0; ct < 8; ++ct) acc[ct] = (f32x4){0.f, 0.f, 0.f, 0.f};

  // ---- root GEMM: rows nb+w*16..+15, A from global xb, B = wrootp ----
  {
    const int node = nb + w * 16 + m;
    short8 afr[4];
#pragma unroll
    for (int ks = 0; ks < 4; ++ks)
      afr[ks] = (node < N) ? *(const short8*)(xb + (size_t)node * 128 + ks * 32 + q * 8) : zero8;
    short8 bf[2][4];
#pragma unroll
    for (int ks = 0; ks < 4; ++ks)
      bf[0][ks] = *(const short8*)(wrootp + ((size_t)((0 * 4 + ks) * 64 + lane)) * 8);
#pragma unroll
    for (int ct = 0; ct < 8; ++ct) {
      if (ct < 7) {
#pragma unroll
        for (int ks = 0; ks < 4; ++ks)
          bf[(ct + 1) & 1][ks] = *(const short8*)(wrootp + ((size_t)(((ct + 1) * 4 + ks) * 64 + lane)) * 8);
      }
#pragma unroll
      for (int ks = 0; ks < 4; ++ks)
        acc[ct] = __builtin_amdgcn_mfma_f32_16x16x32_bf16(afr[ks], bf[ct & 1][ks], acc[ct], 0, 0, 0);
    }
  }

  // ---- relation loop: no barriers ----
  for (int r = 0; r < R_; ++r) {
    // issue descriptors for r+1 early
    const int sN = eCur;
    const int eN = (r < R_ - 1) ? __builtin_amdgcn_readlane(evE, r + 1) : eCur;
    u32 evN = 0;
    if (r < R_ - 1) evN = srt[sN + m];

    // consume xv(r): run-detection; flush non-empty rows; build row mask
    u32 mask = 0;
    {
      int curRow = -1, rc = 0;
      float v0 = 0.f, v1 = 0.f;
#pragma unroll
      for (int j = 0; j < CAP; ++j) {
        if (j < nB) {
          int e = __builtin_amdgcn_readlane((int)evC, j);
          int tl = (e >> 16) & 15;
          if (tl != curRow) {
            if (rc > 0) {
              float sc = 1.0f / (float)rc;
              *(u32*)(myAgg + (size_t)curRow * 136 + 2 * lane) = pk2(v0 * sc, v1 * sc);
            }
            curRow = tl; v0 = 0.f; v1 = 0.f; rc = 0;
            mask |= 1u << tl;
          }
          v0 += __uint_as_float(xv[j] << 16);
          v1 += __uint_as_float(xv[j] & 0xFFFF0000u);
          ++rc;
        }
      }
      for (int p = sCur + CAP; p < eCur; ++p) {   // rare overflow tail
        u32 e = srt[p];
        u32 xvv = *(const u32*)(xb + (size_t)(e & 0xFFFFu) * 128 + 2 * lane);
        int tl = (int)((e >> 16) & 15);
        if (tl != curRow) {
          if (rc > 0) {
            float sc = 1.0f / (float)rc;
            *(u32*)(myAgg + (size_t)curRow * 136 + 2 * lane) = pk2(v0 * sc, v1 * sc);
          }
          curRow = tl; v0 = 0.f; v1 = 0.f; rc = 0;
          mask |= 1u << tl;
        }
        v0 += __uint_as_float(xvv << 16);
        v1 += __uint_as_float(xvv & 0xFFFF0000u);
        ++rc;
      }
      if (rc > 0) {
        float sc = 1.0f / (float)rc;
        *(u32*)(myAgg + (size_t)curRow * 136 + 2 * lane) = pk2(v0 * sc, v1 * sc);
      }
    }

    // issue gathers for r+1 (in flight across the GEMM below)
    const int nBn = (r < R_ - 1) ? min(eN - sN, CAP) : 0;
#pragma unroll
    for (int j = 0; j < CAP; ++j) {
      if (j < nBn) {
        int e = __builtin_amdgcn_readlane((int)evN, j);
        xv[j] = *(const u32*)(xb + (size_t)(e & 0xFFFF) * 128 + 2 * lane);
      }
    }

    // GEMM(r): A from private LDS (mask-selected), B double-staged from wp
    if (mask) {
      short8 af[4];
      const bool live = (mask >> m) & 1;
#pragma unroll
      for (int ks = 0; ks < 4; ++ks) {
        short8 v = *(const short8*)(myAgg + (size_t)m * 136 + ks * 32 + q * 8);
        af[ks] = live ? v : zero8;
      }
      const u16* wr = wp + (size_t)r * 8 * 4 * 64 * 8;
      short8 bf[2][4];
#pragma unroll
      for (int ks = 0; ks < 4; ++ks)
        bf[0][ks] = *(const short8*)(wr + ((size_t)((0 * 4 + ks) * 64 + lane)) * 8);
#pragma unroll
      for (int ct = 0; ct < 8; ++ct) {
        if (ct < 7) {
#pragma unroll
          for (int ks = 0; ks < 4; ++ks)
            bf[(ct + 1) & 1][ks] = *(const short8*)(wr + ((size_t)(((ct + 1) * 4 + ks) * 64 + lane)) * 8);
        }
#pragma unroll
        for (int ks = 0; ks < 4; ++ks)
          acc[ct] = __builtin_amdgcn_mfma_f32_16x16x32_bf16(af[ks], bf[ct & 1][ks], acc[ct], 0, 0, 0);
      }
    }

    sCur = sN; eCur = eN; evC = evN; nB = nBn;
  }

  // ---- epilogue: bias + relu + store h (fp32), rows nb+w*16+q*4+g ----
#pragma unroll
  for (int ct = 0; ct < 8; ++ct) {
    const int col = ct * 16 + m;
    const float bv = bias[col];
#pragma unroll
    for (int g = 0; g < 4; ++g) {
      const int row = nb + w * 16 + q * 4 + g;
      if (row < N) {
        float v = acc[ct][g] + bv;
        h[(size_t)row * 128 + col] = v > 0.f ? v : 0.f;
      }
    }
  }
}

// ---- DistMult scoring: one wave per triplet, float2 loads ----
__global__ void k_score(const float* __restrict__ h, const float* __restrict__ rel_emb,
                        const int* __restrict__ head, const int* __restrict__ tail,
                        const int* __restrict__ rel, float* __restrict__ out, int T) {
  int lane = threadIdx.x & 63, w = threadIdx.x >> 6;
  int gid = blockIdx.x * 4 + w;
  if (gid >= T) return;
  const float2 h2 = *(const float2*)(h + (size_t)head[gid] * 128 + 2 * lane);
  const float2 t2 = *(const float2*)(h + (size_t)tail[gid] * 128 + 2 * lane);
  const float2 r2 = *(const float2*)(rel_emb + (size_t)rel[gid] * 128 + 2 * lane);
  float s = h2.x * r2.x * t2.x + h2.y * r2.y * t2.y;
#pragma unroll
  for (int off = 32; off > 0; off >>= 1) s += __shfl_down(s, off);
  if (lane == 0) out[gid] = s;
}

extern "C" void kernel_launch(void* const* d_in, const int* in_sizes, int n_in,
                              void* d_out, int out_size, void* d_ws, size_t ws_size,
                              hipStream_t stream) {
  const float* x     = (const float*)d_in[0];
  const float* W     = (const float*)d_in[1];
  const float* Wroot = (const float*)d_in[2];
  const float* bias  = (const float*)d_in[3];
  const float* relE  = (const float*)d_in[4];
  const int* ei      = (const int*)d_in[5];
  const int* et      = (const int*)d_in[6];
  const int* headI   = (const int*)d_in[7];
  const int* tailI   = (const int*)d_in[8];
  const int* relI    = (const int*)d_in[9];
  float* out = (float*)d_out;

  const int N = in_sizes[0] / 128;   // 50000
  const int E = in_sizes[6];         // 600000
  const int T = in_sizes[7];         // 8192
  const int NB = (N + 63) >> 6;      // 782
  const int NKEYS = NB * KEYS_PER_B;

  char* p = (char*)d_ws;
  auto alloc = [&](size_t bytes) -> void* {
    void* r = (void*)p;
    p += (bytes + 255) & ~(size_t)255;
    return r;
  };
  u16* xb     = (u16*)alloc((size_t)N * 128 * 2);
  u16* wp     = (u16*)alloc((size_t)32 * 2048 * 8 * 2);
  u16* wrootp = (u16*)alloc((size_t)2048 * 8 * 2);
  int* hist   = (int*)alloc((size_t)NKEYS * 4);
  int* offs   = (int*)alloc((size_t)NKEYS * 4);
  u32* sorted = (u32*)alloc(((size_t)NB * SORT_STRIDE + 64) * 4);  // +pad for unclamped reads
  float* h    = (float*)alloc((size_t)N * 128 * 4);

  const int n4 = N * 128 / 4;
  const int convNB = (n4 + 255) / 256;
  const int packNB = (33 * 2048 + 255) / 256;
  const int histNB = (E / 4 + 255) / 256;

  hipMemsetAsync(hist, 0, (size_t)NKEYS * 4, stream);
  k_pre<<<convNB + packNB + histNB, 256, 0, stream>>>(x, W, Wroot, ei, et, xb, wp, wrootp,
                                                      hist, n4, E, convNB, packNB);
  k_scan_local<<<NB, 256, 0, stream>>>(hist, offs);
  k_scatter<<<(E / 4 + 255) / 256, 256, 0, stream>>>(ei, et, offs, sorted, E);
  k_batch<<<NB, 256, 0, stream>>>(xb, wp, wrootp, bias, sorted, offs, h, N);
  k_score<<<(T + 3) / 4, 256, 0, stream>>>(h, relE, headI, tailI, relI, out, T);
}

// Round 6
// 361.523 us; speedup vs baseline: 1.3168x; 1.3168x over previous
//
#include <hip/hip_runtime.h>
#include <hip/hip_bf16.h>

typedef unsigned int u32;
typedef unsigned long long u64;
typedef unsigned short u16;
typedef short short8 __attribute__((ext_vector_type(8)));
typedef float f32x4 __attribute__((ext_vector_type(4)));
typedef float f32x16 __attribute__((ext_vector_type(16)));

#define R_ 32
#define KEYS_PER_B 2048     // 32 relations * 64 rows per batch
#define SORT_STRIDE 1024    // fixed per-chunk slots in sorted[] (mean 767, +9 sigma)

static __device__ __forceinline__ u16 f2bf(float f) {
  u32 u = __float_as_uint(f);
  u = (u + 0x7FFFu + ((u >> 16) & 1u)) >> 16;   // RNE
  return (u16)u;
}
static __device__ __forceinline__ u32 pk2(float a, float b) {
  __hip_bfloat162 h2 = __float22bfloat162_rn(make_float2(a, b));
  union { __hip_bfloat162 h; u32 u; } cv; cv.h = h2; return cv.u;
}

static __device__ __forceinline__ int sort_key(int tgt, int r) {
  return (tgt >> 6) * KEYS_PER_B + r * 64 + (tgt & 63);
}

// ---- fused: x fp32->bf16 convert + W/W_root pack (32x32x16 B-frag order) + hist ----
// wp frame f = (rel*4 + ct)*8 + ks holds B[k][n]: n = lane&31, k = ks*16 + (lane>>5)*8 + j
__global__ void k_pre(const float* __restrict__ x, const float* __restrict__ W,
                      const float* __restrict__ Wroot, const int* __restrict__ ei,
                      const int* __restrict__ et, u16* __restrict__ xb,
                      u16* __restrict__ wp, int* __restrict__ hist,
                      int n4, int E, int convNB, int packNB) {
  const int bb = (int)blockIdx.x;
  if (bb < convNB) {
    int i = bb * 256 + threadIdx.x;
    if (i >= n4) return;
    const float4 f = ((const float4*)x)[i];
    u32 lo = (u32)f2bf(f.x) | ((u32)f2bf(f.y) << 16);
    u32 hi = (u32)f2bf(f.z) | ((u32)f2bf(f.w) << 16);
    ((uint2*)xb)[i] = make_uint2(lo, hi);
  } else if (bb < convNB + packNB) {
    int tid = (bb - convNB) * 256 + threadIdx.x;
    if (tid >= 33 * 2048) return;
    int lane = tid & 63;
    int ks = (tid >> 6) & 7;
    int ct = (tid >> 9) & 3;
    int rr = tid >> 11;
    int i0 = ks * 16 + (lane >> 5) * 8;
    int o  = ct * 32 + (lane & 31);
    const float* src = (rr < 32) ? (W + (size_t)rr * (128 * 128)) : Wroot;
    u16* dst = wp + ((size_t)((rr * 4 + ct) * 8 + ks) * 64 + lane) * 8;
#pragma unroll
    for (int j = 0; j < 8; ++j) dst[j] = f2bf(src[(size_t)(i0 + j) * 128 + o]);
  } else {
    int e4 = ((bb - convNB - packNB) * 256 + threadIdx.x) * 4;
    if (e4 >= E) return;
    const int4 tg = *(const int4*)(ei + E + e4);
    const int4 rt = *(const int4*)(et + e4);
    atomicAdd(hist + sort_key(tg.x, rt.x), 1);
    atomicAdd(hist + sort_key(tg.y, rt.y), 1);
    atomicAdd(hist + sort_key(tg.z, rt.z), 1);
    atomicAdd(hist + sort_key(tg.w, rt.w), 1);
  }
}

// ---- per-chunk exclusive scan (chunk = 2048 keys = one batch) ----
__global__ __launch_bounds__(256) void k_scan_local(const int* __restrict__ hist,
                                                    int* __restrict__ offs) {
  __shared__ int wsum[4];
  int b = blockIdx.x, t = threadIdx.x;
  size_t base = (size_t)b * KEYS_PER_B + (size_t)t * 8;
  int4 a = *(const int4*)(hist + base);
  int4 c = *(const int4*)(hist + base + 4);
  int v[8] = {a.x, a.y, a.z, a.w, c.x, c.y, c.z, c.w};
  int s = 0;
#pragma unroll
  for (int i = 0; i < 8; ++i) s += v[i];
  int lane = t & 63, w = t >> 6;
  int x = s;
#pragma unroll
  for (int off = 1; off < 64; off <<= 1) {
    int y = __shfl_up(x, off);
    if (lane >= off) x += y;
  }
  if (lane == 63) wsum[w] = x;
  __syncthreads();
  int wb = 0;
  for (int i = 0; i < w; ++i) wb += wsum[i];
  int ex = wb + x - s;
  int o[8];
#pragma unroll
  for (int i = 0; i < 8; ++i) { o[i] = ex; ex += v[i]; }
  *(int4*)(offs + base) = make_int4(o[0], o[1], o[2], o[3]);
  *(int4*)(offs + base + 4) = make_int4(o[4], o[5], o[6], o[7]);
}

// ---- scatter (4 edges/thread); offs[key] becomes per-key chunk-local END ----
__global__ void k_scatter(const int* __restrict__ ei, const int* __restrict__ et,
                          int* __restrict__ offs, u32* __restrict__ sorted, int E) {
  int e4 = (blockIdx.x * 256 + threadIdx.x) * 4;
  if (e4 >= E) return;
  const int4 sr = *(const int4*)(ei + e4);
  const int4 tg = *(const int4*)(ei + E + e4);
  const int4 rt = *(const int4*)(et + e4);
#pragma unroll
  for (int j = 0; j < 4; ++j) {
    int src = (&sr.x)[j], tgt = (&tg.x)[j], r = (&rt.x)[j];
    int p = atomicAdd(offs + sort_key(tgt, r), 1);
    if (p < SORT_STRIDE)
      sorted[(size_t)(tgt >> 6) * SORT_STRIDE + p] = (u32)src | ((u32)(tgt & 63) << 16);
  }
}

// ---- main batch kernel: relation-per-wave, zero barriers in main loop ----
// Wave w owns relations w*8..w*8+7 of its 64-node batch. Per relation: consume
// prefetched gathers (run-detect over sorted rows) into wave-private swizzled
// 64x128 LDS tile, then 64 MFMAs (32x32x16) over all 128 cols; acc (128 VGPR)
// persists across relations. Root GEMM: each wave adds col-tile w only.
// Epilogue: LDS cross-wave reduction + bias + relu.
__global__ __launch_bounds__(256, 2) void k_batch(
    const u16* __restrict__ xb, const u16* __restrict__ wp,
    const float* __restrict__ bias, const u32* __restrict__ sorted,
    const int* __restrict__ offs, float* __restrict__ h, int N) {
  __shared__ u16 aggb[4][64 * 128];   // 65536 B total (swizzled rows)
  const int b = blockIdx.x, t = threadIdx.x;
  const int lane = t & 63, w = t >> 6;
  const int l31 = lane & 31, lh = lane >> 5;
  const int nb = b * 64;
  const int keyBase = b * KEYS_PER_B;
  const u32* srt = sorted + (size_t)b * SORT_STRIDE;
  u16* myAgg = &aggb[w][0];
  const short8 zero8 = {0, 0, 0, 0, 0, 0, 0, 0};

  // wave's 8 relation segment ends (per-lane table) + start
  const int myEnd = offs[keyBase + (w * 8 + (lane & 7)) * 64 + 63];
  int sCur = (w == 0) ? 0 : offs[keyBase + w * 512 - 1];
  int eCur = __builtin_amdgcn_readlane(myEnd, 0);
  int sNext = eCur;
  int eNext = __builtin_amdgcn_readlane(myEnd, 1);

  // ev(0), ev(1), xv(0)
  u32 evC = srt[sCur + lane];
  u32 evN = srt[sNext + lane];
  int nB = min(eCur - sCur, 64);
  u32 xv[32];
#pragma unroll
  for (int j = 0; j < 32; ++j) {
    if (j < nB) {
      int e = __builtin_amdgcn_readlane((int)evC, j);
      xv[j] = *(const u32*)(xb + (size_t)(e & 0xFFFF) * 128 + 2 * lane);
    }
  }

  f32x16 acc[2][4];
#pragma unroll
  for (int rt = 0; rt < 2; ++rt)
#pragma unroll
    for (int ct = 0; ct < 4; ++ct)
#pragma unroll
      for (int k = 0; k < 16; ++k) acc[rt][ct][k] = 0.f;

  // ---- root GEMM: this wave adds only col-tile ct == w (added once block-wide) ----
  {
    const int node0 = nb + l31, node1 = nb + 32 + l31;
#pragma unroll
    for (int ks = 0; ks < 8; ++ks) {
      short8 a0 = (node0 < N) ? *(const short8*)(xb + (size_t)node0 * 128 + ks * 16 + lh * 8) : zero8;
      short8 a1 = (node1 < N) ? *(const short8*)(xb + (size_t)node1 * 128 + ks * 16 + lh * 8) : zero8;
      short8 bf = *(const short8*)(wp + ((size_t)((32 * 4 + w) * 8 + ks) * 64 + lane) * 8);
#pragma unroll
      for (int ct = 0; ct < 4; ++ct) {
        if (ct == w) {
          acc[0][ct] = __builtin_amdgcn_mfma_f32_32x32x16_bf16(a0, bf, acc[0][ct], 0, 0, 0);
          acc[1][ct] = __builtin_amdgcn_mfma_f32_32x32x16_bf16(a1, bf, acc[1][ct], 0, 0, 0);
        }
      }
    }
  }

  // ---- relation loop (8 per wave), no barriers ----
  for (int r = 0; r < 8; ++r) {
    const int relIdx = w * 8 + r;

    // consume(r): run-detection over sorted rows; swizzled flush; row mask
    u64 mask = 0ull;
    int curRow = -1, rc = 0;
    float v0 = 0.f, v1 = 0.f;
#pragma unroll
    for (int j = 0; j < 32; ++j) {
      if (j < nB) {
        int e = __builtin_amdgcn_readlane((int)evC, j);
        int tl = (e >> 16) & 63;
        if (tl != curRow) {
          if (rc > 0) {
            float sc = 1.0f / (float)rc;
            int a = curRow * 128 + ((((lane >> 2) ^ (curRow & 15)) << 3) | ((2 * lane) & 7));
            *(u32*)(myAgg + a) = pk2(v0 * sc, v1 * sc);
          }
          curRow = tl; v0 = 0.f; v1 = 0.f; rc = 0;
          mask |= 1ull << tl;
        }
        v0 += __uint_as_float(xv[j] << 16);
        v1 += __uint_as_float(xv[j] & 0xFFFF0000u);
        ++rc;
      }
    }
    if (nB > 32) {           // second chunk j=32..47 (descriptors still in evC)
      u32 xv2[16];
#pragma unroll
      for (int j = 0; j < 16; ++j) {
        if (32 + j < nB) {
          int e = __builtin_amdgcn_readlane((int)evC, 32 + j);
          xv2[j] = *(const u32*)(xb + (size_t)(e & 0xFFFF) * 128 + 2 * lane);
        }
      }
#pragma unroll
      for (int j = 0; j < 16; ++j) {
        if (32 + j < nB) {
          int e = __builtin_amdgcn_readlane((int)evC, 32 + j);
          int tl = (e >> 16) & 63;
          if (tl != curRow) {
            if (rc > 0) {
              float sc = 1.0f / (float)rc;
              int a = curRow * 128 + ((((lane >> 2) ^ (curRow & 15)) << 3) | ((2 * lane) & 7));
              *(u32*)(myAgg + a) = pk2(v0 * sc, v1 * sc);
            }
            curRow = tl; v0 = 0.f; v1 = 0.f; rc = 0;
            mask |= 1ull << tl;
          }
          v0 += __uint_as_float(xv2[j] << 16);
          v1 += __uint_as_float(xv2[j] & 0xFFFF0000u);
          ++rc;
        }
      }
      for (int p = sCur + 48; p < eCur; ++p) {   // very rare serial tail
        u32 e = srt[p];
        u32 xvv = *(const u32*)(xb + (size_t)(e & 0xFFFFu) * 128 + 2 * lane);
        int tl = (int)((e >> 16) & 63);
        if (tl != curRow) {
          if (rc > 0) {
            float sc = 1.0f / (float)rc;
            int a = curRow * 128 + ((((lane >> 2) ^ (curRow & 15)) << 3) | ((2 * lane) & 7));
            *(u32*)(myAgg + a) = pk2(v0 * sc, v1 * sc);
          }
          curRow = tl; v0 = 0.f; v1 = 0.f; rc = 0;
          mask |= 1ull << tl;
        }
        v0 += __uint_as_float(xvv << 16);
        v1 += __uint_as_float(xvv & 0xFFFF0000u);
        ++rc;
      }
    }
    if (rc > 0) {
      float sc = 1.0f / (float)rc;
      int a = curRow * 128 + ((((lane >> 2) ^ (curRow & 15)) << 3) | ((2 * lane) & 7));
      *(u32*)(myAgg + a) = pk2(v0 * sc, v1 * sc);
    }

    // prefetch xv(r+1) from evN — stays in flight across GEMM(r)
    int nBn = 0;
    if (r < 7) {
      nBn = min(eNext - sNext, 64);
#pragma unroll
      for (int j = 0; j < 32; ++j) {
        if (j < nBn) {
          int e = __builtin_amdgcn_readlane((int)evN, j);
          xv[j] = *(const u32*)(xb + (size_t)(e & 0xFFFF) * 128 + 2 * lane);
        }
      }
    }
    // rotate descriptor regs; issue ev(r+2)
    const int sN2 = eNext;
    const int eN2 = (r + 2 <= 7) ? __builtin_amdgcn_readlane(myEnd, r + 2) : eNext;
    evC = evN;
    if (r < 6) evN = srt[sN2 + lane];

    // GEMM(relIdx): A from swizzled private LDS (mask-selected), B streamed from wp
    if (mask) {
      const bool live0 = (mask >> l31) & 1ull;
      const bool live1 = (mask >> (32 + l31)) & 1ull;
      const u16* wr = wp + (size_t)relIdx * 32 * 64 * 8;
      short8 bf[2][4];
#pragma unroll
      for (int ct = 0; ct < 4; ++ct)
        bf[0][ct] = *(const short8*)(wr + ((size_t)(ct * 8 + 0) * 64 + lane) * 8);
#pragma unroll
      for (int ks = 0; ks < 8; ++ks) {
        if (ks < 7) {
#pragma unroll
          for (int ct = 0; ct < 4; ++ct)
            bf[(ks + 1) & 1][ct] = *(const short8*)(wr + ((size_t)(ct * 8 + ks + 1) * 64 + lane) * 8);
        }
        const int sw = ((2 * ks + lh) ^ (l31 & 15)) << 3;
        short8 a0 = *(const short8*)(myAgg + (size_t)l31 * 128 + sw);
        short8 a1 = *(const short8*)(myAgg + (size_t)(32 + l31) * 128 + sw);
        a0 = live0 ? a0 : zero8;
        a1 = live1 ? a1 : zero8;
#pragma unroll
        for (int ct = 0; ct < 4; ++ct) {
          acc[0][ct] = __builtin_amdgcn_mfma_f32_32x32x16_bf16(a0, bf[ks & 1][ct], acc[0][ct], 0, 0, 0);
          acc[1][ct] = __builtin_amdgcn_mfma_f32_32x32x16_bf16(a1, bf[ks & 1][ct], acc[1][ct], 0, 0, 0);
        }
      }
    }

    sCur = sNext; eCur = eNext; sNext = sN2; eNext = eN2; nB = nBn;
  }

  // ---- epilogue: cross-wave reduction in LDS (swizzled), + bias + relu ----
  __syncthreads();
  float* red = (float*)&aggb[0][0];   // 4 regions of 4096 floats
  float* myRed = red + w * 4096;
#pragma unroll
  for (int g = 0; g < 2; ++g) {
#pragma unroll
    for (int ct = 0; ct < 4; ++ct) {
#pragma unroll
      for (int reg = 0; reg < 16; ++reg) {
        int row = (reg & 3) + 8 * (reg >> 2) + 4 * lh;
        int col = ct * 32 + l31;
        myRed[row * 128 + ((((col >> 2) ^ (row & 31)) << 2) | (col & 3))] = acc[g][ct][reg];
      }
    }
    __syncthreads();
    {
      const int row = t & 31, cb0 = (t >> 5) * 16;
      const int grow = nb + g * 32 + row;
#pragma unroll
      for (int v = 0; v < 4; ++v) {
        const int col = cb0 + v * 4;
        const int idx = row * 128 + ((((col >> 2) ^ (row & 31)) << 2));
        f32x4 s = *(f32x4*)(red + idx);
        s += *(f32x4*)(red + 4096 + idx);
        s += *(f32x4*)(red + 8192 + idx);
        s += *(f32x4*)(red + 12288 + idx);
        const float4 bb = *(const float4*)(bias + col);
        s[0] = fmaxf(s[0] + bb.x, 0.f);
        s[1] = fmaxf(s[1] + bb.y, 0.f);
        s[2] = fmaxf(s[2] + bb.z, 0.f);
        s[3] = fmaxf(s[3] + bb.w, 0.f);
        if (grow < N) *(f32x4*)(h + (size_t)grow * 128 + col) = s;
      }
    }
    if (g == 0) __syncthreads();
  }
}

// ---- DistMult scoring: one wave per triplet, float2 loads ----
__global__ void k_score(const float* __restrict__ h, const float* __restrict__ rel_emb,
                        const int* __restrict__ head, const int* __restrict__ tail,
                        const int* __restrict__ rel, float* __restrict__ out, int T) {
  int lane = threadIdx.x & 63, w = threadIdx.x >> 6;
  int gid = blockIdx.x * 4 + w;
  if (gid >= T) return;
  const float2 h2 = *(const float2*)(h + (size_t)head[gid] * 128 + 2 * lane);
  const float2 t2 = *(const float2*)(h + (size_t)tail[gid] * 128 + 2 * lane);
  const float2 r2 = *(const float2*)(rel_emb + (size_t)rel[gid] * 128 + 2 * lane);
  float s = h2.x * r2.x * t2.x + h2.y * r2.y * t2.y;
#pragma unroll
  for (int off = 32; off > 0; off >>= 1) s += __shfl_down(s, off);
  if (lane == 0) out[gid] = s;
}

extern "C" void kernel_launch(void* const* d_in, const int* in_sizes, int n_in,
                              void* d_out, int out_size, void* d_ws, size_t ws_size,
                              hipStream_t stream) {
  const float* x     = (const float*)d_in[0];
  const float* W     = (const float*)d_in[1];
  const float* Wroot = (const float*)d_in[2];
  const float* bias  = (const float*)d_in[3];
  const float* relE  = (const float*)d_in[4];
  const int* ei      = (const int*)d_in[5];
  const int* et      = (const int*)d_in[6];
  const int* headI   = (const int*)d_in[7];
  const int* tailI   = (const int*)d_in[8];
  const int* relI    = (const int*)d_in[9];
  float* out = (float*)d_out;

  const int N = in_sizes[0] / 128;   // 50000
  const int E = in_sizes[6];         // 600000
  const int T = in_sizes[7];         // 8192
  const int NB = (N + 63) >> 6;      // 782
  const int NKEYS = NB * KEYS_PER_B;

  char* p = (char*)d_ws;
  auto alloc = [&](size_t bytes) -> void* {
    void* r = (void*)p;
    p += (bytes + 255) & ~(size_t)255;
    return r;
  };
  u16* xb     = (u16*)alloc((size_t)N * 128 * 2);            // 12.8 MB
  u16* wp     = (u16*)alloc((size_t)33 * 2048 * 8 * 2);      // 1.08 MB (rel 32 = root)
  int* hist   = (int*)alloc((size_t)NKEYS * 4);              // 6.4 MB
  int* offs   = (int*)alloc((size_t)NKEYS * 4);              // 6.4 MB
  u32* sorted = (u32*)alloc(((size_t)NB * SORT_STRIDE + 64) * 4);
  float* h    = (float*)alloc((size_t)N * 128 * 4);          // 25.6 MB

  const int n4 = N * 128 / 4;
  const int convNB = (n4 + 255) / 256;
  const int packNB = (33 * 2048 + 255) / 256;
  const int histNB = (E / 4 + 255) / 256;

  hipMemsetAsync(hist, 0, (size_t)NKEYS * 4, stream);
  k_pre<<<convNB + packNB + histNB, 256, 0, stream>>>(x, W, Wroot, ei, et, xb, wp,
                                                      hist, n4, E, convNB, packNB);
  k_scan_local<<<NB, 256, 0, stream>>>(hist, offs);
  k_scatter<<<(E / 4 + 255) / 256, 256, 0, stream>>>(ei, et, offs, sorted, E);
  k_batch<<<NB, 256, 0, stream>>>(xb, wp, bias, sorted, offs, h, N);
  k_score<<<(T + 3) / 4, 256, 0, stream>>>(h, relE, headI, tailI, relI, out, T);
}

// Round 7
// 334.367 us; speedup vs baseline: 1.4237x; 1.0812x over previous
//
#include <hip/hip_runtime.h>
#include <hip/hip_bf16.h>

typedef unsigned int u32;
typedef unsigned short u16;
typedef short short8 __attribute__((ext_vector_type(8)));
typedef float f32x4 __attribute__((ext_vector_type(4)));
typedef float f32x16 __attribute__((ext_vector_type(16)));

#define R_ 32
#define KEYS_PER_B 2048     // 32 relations * 64 rows per batch
#define SORT_STRIDE 1024    // fixed per-chunk slots in sorted[] (mean 767, +9 sigma)

static __device__ __forceinline__ u16 f2bf(float f) {
  u32 u = __float_as_uint(f);
  u = (u + 0x7FFFu + ((u >> 16) & 1u)) >> 16;   // RNE
  return (u16)u;
}
static __device__ __forceinline__ u32 pk2(float a, float b) {
  __hip_bfloat162 h2 = __float22bfloat162_rn(make_float2(a, b));
  union { __hip_bfloat162 h; u32 u; } cv; cv.h = h2; return cv.u;
}

static __device__ __forceinline__ int sort_key(int tgt, int r) {
  return (tgt >> 6) * KEYS_PER_B + r * 64 + (tgt & 63);
}

// ---- fused: x fp32->bf16 convert + W/W_root pack (32x32x16 B-frag order) + hist ----
// wp frame (rr*4+ct)*8+ks holds B[k][n]: n = ct*32 + (lane&31), k = ks*16 + (lane>>5)*8 + j
__global__ void k_pre(const float* __restrict__ x, const float* __restrict__ W,
                      const float* __restrict__ Wroot, const int* __restrict__ ei,
                      const int* __restrict__ et, u16* __restrict__ xb,
                      u16* __restrict__ wp, int* __restrict__ hist,
                      int n4, int E, int convNB, int packNB) {
  const int bb = (int)blockIdx.x;
  if (bb < convNB) {
    int i = bb * 256 + threadIdx.x;
    if (i >= n4) return;
    const float4 f = ((const float4*)x)[i];
    u32 lo = (u32)f2bf(f.x) | ((u32)f2bf(f.y) << 16);
    u32 hi = (u32)f2bf(f.z) | ((u32)f2bf(f.w) << 16);
    ((uint2*)xb)[i] = make_uint2(lo, hi);
  } else if (bb < convNB + packNB) {
    int tid = (bb - convNB) * 256 + threadIdx.x;
    if (tid >= 33 * 2048) return;
    int lane = tid & 63;
    int ks = (tid >> 6) & 7;
    int ct = (tid >> 9) & 3;
    int rr = tid >> 11;
    int i0 = ks * 16 + (lane >> 5) * 8;
    int o  = ct * 32 + (lane & 31);
    const float* src = (rr < 32) ? (W + (size_t)rr * (128 * 128)) : Wroot;
    u16* dst = wp + ((size_t)((rr * 4 + ct) * 8 + ks) * 64 + lane) * 8;
#pragma unroll
    for (int j = 0; j < 8; ++j) dst[j] = f2bf(src[(size_t)(i0 + j) * 128 + o]);
  } else {
    int e4 = ((bb - convNB - packNB) * 256 + threadIdx.x) * 4;
    if (e4 >= E) return;
    const int4 tg = *(const int4*)(ei + E + e4);
    const int4 rt = *(const int4*)(et + e4);
    atomicAdd(hist + sort_key(tg.x, rt.x), 1);
    atomicAdd(hist + sort_key(tg.y, rt.y), 1);
    atomicAdd(hist + sort_key(tg.z, rt.z), 1);
    atomicAdd(hist + sort_key(tg.w, rt.w), 1);
  }
}

// ---- per-chunk exclusive scan (chunk = 2048 keys = one batch) ----
__global__ __launch_bounds__(256) void k_scan_local(const int* __restrict__ hist,
                                                    int* __restrict__ offs) {
  __shared__ int wsum[4];
  int b = blockIdx.x, t = threadIdx.x;
  size_t base = (size_t)b * KEYS_PER_B + (size_t)t * 8;
  int4 a = *(const int4*)(hist + base);
  int4 c = *(const int4*)(hist + base + 4);
  int v[8] = {a.x, a.y, a.z, a.w, c.x, c.y, c.z, c.w};
  int s = 0;
#pragma unroll
  for (int i = 0; i < 8; ++i) s += v[i];
  int lane = t & 63, w = t >> 6;
  int x = s;
#pragma unroll
  for (int off = 1; off < 64; off <<= 1) {
    int y = __shfl_up(x, off);
    if (lane >= off) x += y;
  }
  if (lane == 63) wsum[w] = x;
  __syncthreads();
  int wb = 0;
  for (int i = 0; i < w; ++i) wb += wsum[i];
  int ex = wb + x - s;
  int o[8];
#pragma unroll
  for (int i = 0; i < 8; ++i) { o[i] = ex; ex += v[i]; }
  *(int4*)(offs + base) = make_int4(o[0], o[1], o[2], o[3]);
  *(int4*)(offs + base + 4) = make_int4(o[4], o[5], o[6], o[7]);
}

// ---- scatter (4 edges/thread); offs[key] becomes per-key chunk-local END ----
__global__ void k_scatter(const int* __restrict__ ei, const int* __restrict__ et,
                          int* __restrict__ offs, u32* __restrict__ sorted, int E) {
  int e4 = (blockIdx.x * 256 + threadIdx.x) * 4;
  if (e4 >= E) return;
  const int4 sr = *(const int4*)(ei + e4);
  const int4 tg = *(const int4*)(ei + E + e4);
  const int4 rt = *(const int4*)(et + e4);
#pragma unroll
  for (int j = 0; j < 4; ++j) {
    int src = (&sr.x)[j], tgt = (&tg.x)[j], r = (&rt.x)[j];
    int p = atomicAdd(offs + sort_key(tgt, r), 1);
    if (p < SORT_STRIDE)
      sorted[(size_t)(tgt >> 6) * SORT_STRIDE + p] = (u32)src | ((u32)(tgt & 63) << 16);
  }
}

// ---- main batch kernel: aggregation VIA MFMA (P @ (Xg @ W_r)), zero barriers ----
// Wave w owns relations w*8..w*8+7, full 64x128 acc. Per relation, per 32-edge
// chunk: Z = Xg@W_r (A-frags = per-lane 16B gathers, W streamed from L2),
// Z -> wave-private transposed LDS (bf16), P built in regs from descriptors
// (one nonzero per edge column = 1/cnt at row tgt), acc += P@Z (16 MFMAs).
// No run-detection, no serial chains, no cross-wave coupling until epilogue.
__global__ __launch_bounds__(256, 2) void k_batch(
    const u16* __restrict__ xb, const u16* __restrict__ wp,
    const float* __restrict__ bias, const u32* __restrict__ sorted,
    const int* __restrict__ offs, float* __restrict__ h, int N) {
  __shared__ u16 smem[4 * 5184];   // per-wave 5184 u16: Zt (128 cols x stride 40) / epilogue
  const int b = blockIdx.x, t = threadIdx.x;
  const int lane = t & 63, w = t >> 6;
  const int l31 = lane & 31, lh = lane >> 5;
  const int nb = b * 64;
  const int keyBase = b * KEYS_PER_B;
  const u32* srt = sorted + (size_t)b * SORT_STRIDE;
  u16* myZt = smem + w * 5184;
  const short8 zero8 = {0, 0, 0, 0, 0, 0, 0, 0};

  // per-lane table of this wave's 8 relation segment ends
  const int myEnd = offs[keyBase + (w * 8 + (lane & 7)) * 64 + 63];
  int sSeg = (w == 0) ? 0 : offs[keyBase + w * 512 - 1];
  int eSeg = __builtin_amdgcn_readlane(myEnd, 0);

  // relation-0 window-0 descriptors + per-lane (tl, norm)
  u32 ev = srt[sSeg + lane];
  int tlv; u32 normu;
  {
    tlv = (int)((ev >> 16) & 63);
    int L = (w * 8) * 64 + tlv;
    int cE = offs[keyBase + L];
    int cS = (L > 0) ? offs[keyBase + L - 1] : 0;
    normu = (lane < eSeg - sSeg) ? (u32)f2bf(1.0f / (float)(cE - cS)) : 0u;
  }
  // A-frag gathers for relation 0 chunk 0: lane l31 = edge, 8 x 16B
  short8 A0[8];
  {
    u32 sr = (u32)__shfl((int)ev, l31) & 0xFFFFu;
    const u16* xp = xb + (size_t)sr * 128 + lh * 8;
#pragma unroll
    for (int ks = 0; ks < 8; ++ks) A0[ks] = *(const short8*)(xp + ks * 16);
  }

  f32x16 acc[2][4];
#pragma unroll
  for (int mt = 0; mt < 2; ++mt)
#pragma unroll
    for (int ct = 0; ct < 4; ++ct)
#pragma unroll
      for (int k = 0; k < 16; ++k) acc[mt][ct][k] = 0.f;

  // ---- root GEMM: wave w computes col-tile w into temp, merged into acc ----
  {
    f32x16 rt0, rt1;
#pragma unroll
    for (int k = 0; k < 16; ++k) { rt0[k] = 0.f; rt1[k] = 0.f; }
    const u16* wrr = wp + (size_t)((32 * 4 + w) * 8) * 64 * 8;
    short8 bfr[8];
#pragma unroll
    for (int ks = 0; ks < 8; ++ks)
      bfr[ks] = *(const short8*)(wrr + ((size_t)ks * 64 + lane) * 8);
#pragma unroll
    for (int mt = 0; mt < 2; ++mt) {
      const int node = nb + mt * 32 + l31;
      const u16* xp = xb + (size_t)node * 128 + lh * 8;
#pragma unroll
      for (int ks = 0; ks < 8; ++ks) {
        short8 a = (node < N) ? *(const short8*)(xp + ks * 16) : zero8;
        if (mt == 0) rt0 = __builtin_amdgcn_mfma_f32_32x32x16_bf16(a, bfr[ks], rt0, 0, 0, 0);
        else         rt1 = __builtin_amdgcn_mfma_f32_32x32x16_bf16(a, bfr[ks], rt1, 0, 0, 0);
      }
    }
#pragma unroll
    for (int ct = 0; ct < 4; ++ct)
      if (w == ct) { acc[0][ct] += rt0; acc[1][ct] += rt1; }
  }

  // ---- relation loop (8 per wave, rolled), no barriers ----
#pragma unroll 1
  for (int r = 0; r < 8; ++r) {
    const int rIdx = w * 8 + r;
    const int sN = eSeg;
    const int eN = (r < 7) ? __builtin_amdgcn_readlane(myEnd, r + 1) : eSeg;
    const u32 evN = srt[sN + lane];           // descriptors for relation r+1
    const int E = eSeg - sSeg;

    if (E > 0) {
      const u16* wr = wp + (size_t)(rIdx * 4 * 8) * 64 * 8;
      const int nChunks = (E + 31) >> 5;
#pragma unroll 1
      for (int c = 0; c < nChunks; ++c) {
        if (c >= 2 && (c & 1) == 0) {       // rare: refresh 64-edge window
          ev = srt[sSeg + (c >> 1) * 64 + lane];
          tlv = (int)((ev >> 16) & 63);
          int L = rIdx * 64 + tlv;
          int cE = offs[keyBase + L];
          int cS = (L > 0) ? offs[keyBase + L - 1] : 0;
          normu = (lane < E - (c >> 1) * 64) ? (u32)f2bf(1.0f / (float)(cE - cS)) : 0u;
        }
        if (c > 0) {                         // gather A-frags for this chunk
          u32 sr = (u32)__shfl((int)ev, ((c & 1) << 5) + l31) & 0xFFFFu;
          const u16* xp = xb + (size_t)sr * 128 + lh * 8;
#pragma unroll
          for (int ks = 0; ks < 8; ++ks) A0[ks] = *(const short8*)(xp + ks * 16);
        }

        // ---- Z-GEMM in two ct-halves (caps register pressure), write Zt ----
#pragma unroll 1
        for (int ch = 0; ch < 2; ++ch) {
          f32x16 Z0, Z1;
#pragma unroll
          for (int k = 0; k < 16; ++k) { Z0[k] = 0.f; Z1[k] = 0.f; }
          const u16* w0 = wr + (size_t)((ch * 2 + 0) * 8) * 64 * 8;
          const u16* w1 = wr + (size_t)((ch * 2 + 1) * 8) * 64 * 8;
          short8 wbuf[3][2];
#pragma unroll
          for (int i = 0; i < 3; ++i) {
            wbuf[i][0] = *(const short8*)(w0 + ((size_t)i * 64 + lane) * 8);
            wbuf[i][1] = *(const short8*)(w1 + ((size_t)i * 64 + lane) * 8);
          }
#pragma unroll
          for (int ks = 0; ks < 8; ++ks) {
            const short8 a = A0[ks];
            Z0 = __builtin_amdgcn_mfma_f32_32x32x16_bf16(a, wbuf[ks % 3][0], Z0, 0, 0, 0);
            Z1 = __builtin_amdgcn_mfma_f32_32x32x16_bf16(a, wbuf[ks % 3][1], Z1, 0, 0, 0);
            if (ks < 5) {
              wbuf[ks % 3][0] = *(const short8*)(w0 + ((size_t)(ks + 3) * 64 + lane) * 8);
              wbuf[ks % 3][1] = *(const short8*)(w1 + ((size_t)(ks + 3) * 64 + lane) * 8);
            }
          }
          // write transposed bf16 Z: Zt[col][k] at col*40 + k (u16 units)
#pragma unroll
          for (int q = 0; q < 4; ++q) {
            // regs 4q..4q+3 hold rows 8q+4lh..+3 (C-layout)
            u32 lo0 = pk2(Z0[4 * q + 0], Z0[4 * q + 1]);
            u32 hi0 = pk2(Z0[4 * q + 2], Z0[4 * q + 3]);
            *(uint2*)(myZt + (size_t)((ch * 2 + 0) * 32 + l31) * 40 + 8 * q + 4 * lh) =
                make_uint2(lo0, hi0);
            u32 lo1 = pk2(Z1[4 * q + 0], Z1[4 * q + 1]);
            u32 hi1 = pk2(Z1[4 * q + 2], Z1[4 * q + 3]);
            *(uint2*)(myZt + (size_t)((ch * 2 + 1) * 32 + l31) * 40 + 8 * q + 4 * lh) =
                make_uint2(lo1, hi1);
          }
        }

        // ---- P-build + P@Z: acc += P[64x32] @ Z[32x128] ----
        const int base = (c & 1) << 5;
#pragma unroll
        for (int ks2 = 0; ks2 < 2; ++ks2) {
          const int i0 = base + ks2 * 16;
          union { u32 u[4]; short8 s; } pf0, pf1;
#pragma unroll
          for (int uu = 0; uu < 4; ++uu) {
            u32 a0 = 0, a1 = 0, b0 = 0, b1 = 0;
#pragma unroll
            for (int jj = 0; jj < 2; ++jj) {
              const int j = uu * 2 + jj;
              int ta = __builtin_amdgcn_readlane(tlv, i0 + j);
              int tb = __builtin_amdgcn_readlane(tlv, i0 + 8 + j);
              int na = __builtin_amdgcn_readlane((int)normu, i0 + j);
              int nbv = __builtin_amdgcn_readlane((int)normu, i0 + 8 + j);
              int tk = lh ? tb : ta;
              u32 nk = (u32)(lh ? nbv : na);
              u32 v0 = (tk == l31) ? nk : 0u;
              u32 v1 = (tk == l31 + 32) ? nk : 0u;
              if (jj == 0) { a0 = v0; a1 = v1; } else { b0 = v0; b1 = v1; }
            }
            pf0.u[uu] = a0 | (b0 << 16);
            pf1.u[uu] = a1 | (b1 << 16);
          }
#pragma unroll
          for (int ct = 0; ct < 4; ++ct) {
            short8 bz = *(const short8*)(myZt + (size_t)(ct * 32 + l31) * 40 + ks2 * 16 + lh * 8);
            acc[0][ct] = __builtin_amdgcn_mfma_f32_32x32x16_bf16(pf0.s, bz, acc[0][ct], 0, 0, 0);
            acc[1][ct] = __builtin_amdgcn_mfma_f32_32x32x16_bf16(pf1.s, bz, acc[1][ct], 0, 0, 0);
          }
        }
      }
    }

    // rotate to relation r+1: window state + A-frag gathers
    if (r < 7) {
      ev = evN;
      tlv = (int)((ev >> 16) & 63);
      int L = (w * 8 + r + 1) * 64 + tlv;
      int cE = offs[keyBase + L];
      int cS = offs[keyBase + L - 1];     // L >= 64 > 0 always here
      normu = (lane < eN - sN) ? (u32)f2bf(1.0f / (float)(cE - cS)) : 0u;
      u32 sr = (u32)__shfl((int)ev, l31) & 0xFFFFu;
      const u16* xp = xb + (size_t)sr * 128 + lh * 8;
#pragma unroll
      for (int ks = 0; ks < 8; ++ks) A0[ks] = *(const short8*)(xp + ks * 16);
      sSeg = sN; eSeg = eN;
    }
  }

  // ---- epilogue: cross-wave reduce (4 regions) + bias + relu, per ct ----
  float* fb = (float*)smem;                  // regions at stride 2592 floats
  float* myRegion = fb + w * 2592;
#pragma unroll 1
  for (int ct = 0; ct < 4; ++ct) {
#pragma unroll
    for (int mt = 0; mt < 2; ++mt) {
      const f32x16 v = acc[mt][ct];
#pragma unroll
      for (int q = 0; q < 4; ++q)
#pragma unroll
        for (int j = 0; j < 4; ++j) {
          const int row = mt * 32 + 8 * q + 4 * lh + j;
          myRegion[row * 32 + l31] = v[4 * q + j];
        }
    }
    __syncthreads();
#pragma unroll
    for (int it = 0; it < 2; ++it) {
      const int fo = (t + it * 256) * 4;     // 2048 floats = 64 rows x 32 cols
      f32x4 s = *(f32x4*)(fb + fo);
      s += *(f32x4*)(fb + 2592 + fo);
      s += *(f32x4*)(fb + 2 * 2592 + fo);
      s += *(f32x4*)(fb + 3 * 2592 + fo);
      const int row = fo >> 5, col0 = (fo & 31) + ct * 32;
      const float4 bv = *(const float4*)(bias + col0);
      s[0] = fmaxf(s[0] + bv.x, 0.f);
      s[1] = fmaxf(s[1] + bv.y, 0.f);
      s[2] = fmaxf(s[2] + bv.z, 0.f);
      s[3] = fmaxf(s[3] + bv.w, 0.f);
      if (nb + row < N) *(f32x4*)(h + (size_t)(nb + row) * 128 + col0) = s;
    }
    __syncthreads();
  }
}

// ---- DistMult scoring: one wave per triplet, float2 loads ----
__global__ void k_score(const float* __restrict__ h, const float* __restrict__ rel_emb,
                        const int* __restrict__ head, const int* __restrict__ tail,
                        const int* __restrict__ rel, float* __restrict__ out, int T) {
  int lane = threadIdx.x & 63, w = threadIdx.x >> 6;
  int gid = blockIdx.x * 4 + w;
  if (gid >= T) return;
  const float2 h2 = *(const float2*)(h + (size_t)head[gid] * 128 + 2 * lane);
  const float2 t2 = *(const float2*)(h + (size_t)tail[gid] * 128 + 2 * lane);
  const float2 r2 = *(const float2*)(rel_emb + (size_t)rel[gid] * 128 + 2 * lane);
  float s = h2.x * r2.x * t2.x + h2.y * r2.y * t2.y;
#pragma unroll
  for (int off = 32; off > 0; off >>= 1) s += __shfl_down(s, off);
  if (lane == 0) out[gid] = s;
}

extern "C" void kernel_launch(void* const* d_in, const int* in_sizes, int n_in,
                              void* d_out, int out_size, void* d_ws, size_t ws_size,
                              hipStream_t stream) {
  const float* x     = (const float*)d_in[0];
  const float* W     = (const float*)d_in[1];
  const float* Wroot = (const float*)d_in[2];
  const float* bias  = (const float*)d_in[3];
  const float* relE  = (const float*)d_in[4];
  const int* ei      = (const int*)d_in[5];
  const int* et      = (const int*)d_in[6];
  const int* headI   = (const int*)d_in[7];
  const int* tailI   = (const int*)d_in[8];
  const int* relI    = (const int*)d_in[9];
  float* out = (float*)d_out;

  const int N = in_sizes[0] / 128;   // 50000
  const int E = in_sizes[6];         // 600000
  const int T = in_sizes[7];         // 8192
  const int NB = (N + 63) >> 6;      // 782
  const int NKEYS = NB * KEYS_PER_B;

  char* p = (char*)d_ws;
  auto alloc = [&](size_t bytes) -> void* {
    void* r = (void*)p;
    p += (bytes + 255) & ~(size_t)255;
    return r;
  };
  u16* xb     = (u16*)alloc((size_t)N * 128 * 2);            // 12.8 MB
  u16* wp     = (u16*)alloc((size_t)33 * 2048 * 8 * 2);      // 1.08 MB (rel 32 = root)
  int* hist   = (int*)alloc((size_t)NKEYS * 4);              // 6.4 MB
  int* offs   = (int*)alloc((size_t)NKEYS * 4);              // 6.4 MB
  u32* sorted = (u32*)alloc(((size_t)NB * SORT_STRIDE + 64) * 4);
  float* h    = (float*)alloc((size_t)N * 128 * 4);          // 25.6 MB

  const int n4 = N * 128 / 4;
  const int convNB = (n4 + 255) / 256;
  const int packNB = (33 * 2048 + 255) / 256;
  const int histNB = (E / 4 + 255) / 256;

  hipMemsetAsync(hist, 0, (size_t)NKEYS * 4, stream);
  k_pre<<<convNB + packNB + histNB, 256, 0, stream>>>(x, W, Wroot, ei, et, xb, wp,
                                                      hist, n4, E, convNB, packNB);
  k_scan_local<<<NB, 256, 0, stream>>>(hist, offs);
  k_scatter<<<(E / 4 + 255) / 256, 256, 0, stream>>>(ei, et, offs, sorted, E);
  k_batch<<<NB, 256, 0, stream>>>(xb, wp, bias, sorted, offs, h, N);
  k_score<<<(T + 3) / 4, 256, 0, stream>>>(h, relE, headI, tailI, relI, out, T);
}